// Round 11
// baseline (1465.149 us; speedup 1.0000x reference)
//
#include <hip/hip_runtime.h>
#include <hip/hip_bf16.h>
#include <math.h>

constexpr int NB = 64;     // batch
constexpr int NS = 2048;   // tokens
constexpr int ND = 1024;   // model dim
constexpr int NE = 32;     // experts
constexpr int NH = 4096;   // hidden
constexpr int NK = 8;      // top-k tokens per expert

// ===== ATTRIBUTION: k_topk amplified x16 with rotated batch per rep (honest,
// deterministic duplicate writes). Everything else = R9 best. Remove next round.
constexpr int TREP = 16;

typedef short bf16x8 __attribute__((ext_vector_type(8)));
typedef float f32x4  __attribute__((ext_vector_type(4)));

__device__ __forceinline__ unsigned short f2bf_rne(float v) {
  unsigned u = __builtin_bit_cast(unsigned, v);
  u += 0x7fffu + ((u >> 16) & 1u);
  return (unsigned short)(u >> 16);
}

__device__ __forceinline__ void gload_lds16(const void* g, void* l) {
  __builtin_amdgcn_global_load_lds(
      (const __attribute__((address_space(1))) unsigned*)g,
      (__attribute__((address_space(3))) unsigned*)l, 16, 0, 0);
}

// ---------------------------------------------------------------------------
// Kernel 1: gating GEMM (R9 T4 form: two register sets, raw s_barrier with
// lgkmcnt-only, x2-unrolled K-loop).
// ---------------------------------------------------------------------------
__global__ __launch_bounds__(256) void k_gate_mfma(const float* __restrict__ x,
                                                   const float* __restrict__ gw,
                                                   float* __restrict__ logitsT) {
  const int b  = blockIdx.y;
  const int s0 = blockIdx.x * 128;
  const int t  = threadIdx.x;
  const int l  = t & 63;
  const int w  = t >> 6;

  __shared__ char smem[40960];
  float* trans = (float*)smem;

  f32x4 acc[2][2] = {};

  const int xr_ = t >> 4, xc = (t & 15) * 4;
  const int ge = t >> 3,  gk = (t & 7) * 8;

  float xA[8][4], xB[8][4], wA[8], wB[8];

  auto issue = [&](int kt, float (&xreg)[8][4], float (&wreg)[8]) {
    const int k0 = kt * 64;
#pragma unroll
    for (int p = 0; p < 8; ++p) {
      const int r = p * 16 + xr_;
      *(float4*)xreg[p] = *(const float4*)&x[((size_t)b * NS + s0 + r) * ND + k0 + xc];
    }
    *(float4*)&wreg[0] = *(const float4*)&gw[(size_t)ge * ND + k0 + gk];
    *(float4*)&wreg[4] = *(const float4*)&gw[(size_t)ge * ND + k0 + gk + 4];
  };
  auto commit = [&](int dst, float (&xreg)[8][4], float (&wreg)[8]) {
    short* Ah = (short*)(smem + dst * 16384);
    short* Bh = (short*)(smem + 32768 + dst * 4096);
#pragma unroll
    for (int p = 0; p < 8; ++p) {
      const int r = p * 16 + xr_;
      unsigned short h[4];
#pragma unroll
      for (int j = 0; j < 4; ++j) h[j] = f2bf_rne(xreg[p][j]);
      const int off = r * 64 + (xc ^ ((r & 7) * 8));
      *(ushort4*)&Ah[off] = *(const ushort4*)h;
    }
    unsigned short h8[8];
#pragma unroll
    for (int j = 0; j < 8; ++j) h8[j] = f2bf_rne(wreg[j]);
    const int boff = ge * 64 + (gk ^ ((ge & 7) * 8));
    *(uint4*)&Bh[boff] = *(const uint4*)h8;
  };
  auto mfma_phase = [&](int cur) {
    const short* Ah = (const short*)(smem + cur * 16384);
    const short* Bh = (const short*)(smem + 32768 + cur * 4096);
#pragma unroll
    for (int ks = 0; ks < 2; ++ks) {
      const int koff = ks * 32 + (l >> 4) * 8;
      bf16x8 a[2], bb[2];
#pragma unroll
      for (int mf = 0; mf < 2; ++mf) {
        const int r = w * 32 + mf * 16 + (l & 15);
        a[mf] = *(const bf16x8*)&Ah[r * 64 + (koff ^ ((r & 7) * 8))];
      }
#pragma unroll
      for (int nf = 0; nf < 2; ++nf) {
        const int n = nf * 16 + (l & 15);
        bb[nf] = *(const bf16x8*)&Bh[n * 64 + (koff ^ ((n & 7) * 8))];
      }
#pragma unroll
      for (int mf = 0; mf < 2; ++mf)
#pragma unroll
        for (int nf = 0; nf < 2; ++nf)
          acc[mf][nf] = __builtin_amdgcn_mfma_f32_16x16x32_bf16(a[mf], bb[nf], acc[mf][nf], 0, 0, 0);
    }
  };
  auto bar = [&]() {
    asm volatile("s_waitcnt lgkmcnt(0)" ::: "memory");
    __builtin_amdgcn_s_barrier();
    __builtin_amdgcn_sched_barrier(0);
  };

  issue(0, xA, wA);
  issue(1, xB, wB);
  commit(0, xA, wA);
  bar();

  for (int kt = 0; kt < ND / 64; kt += 2) {
    if (kt + 2 < ND / 64) issue(kt + 2, xA, wA);
    commit(1, xB, wB);
    mfma_phase(0);
    bar();
    if (kt + 3 < ND / 64) issue(kt + 3, xB, wB);
    if (kt + 2 < ND / 64) commit(0, xA, wA);
    mfma_phase(1);
    bar();
  }

#pragma unroll
  for (int mf = 0; mf < 2; ++mf)
#pragma unroll
    for (int nf = 0; nf < 2; ++nf)
#pragma unroll
      for (int j = 0; j < 4; ++j) {
        const int sl = w * 32 + mf * 16 + (l >> 4) * 4 + j;
        const int ec = nf * 16 + (l & 15);
        trans[sl * 33 + ec] = acc[mf][nf][j];
      }
  __syncthreads();
  const int eo = t >> 3, sc = (t & 7) * 16;
#pragma unroll
  for (int j4 = 0; j4 < 4; ++j4) {
    float4 v;
    v.x = trans[(sc + j4 * 4 + 0) * 33 + eo];
    v.y = trans[(sc + j4 * 4 + 1) * 33 + eo];
    v.z = trans[(sc + j4 * 4 + 2) * 33 + eo];
    v.w = trans[(sc + j4 * 4 + 3) * 33 + eo];
    *(float4*)&logitsT[((size_t)b * NE + eo) * NS + s0 + sc + j4 * 4] = v;
  }
}

// ---------------------------------------------------------------------------
// Kernel 2: topk — TREP× amplified, batch rotated per rep (honest traffic,
// identical duplicate outputs).
// ---------------------------------------------------------------------------
__global__ __launch_bounds__(256) void k_topk(const float* __restrict__ logitsT,
                                              const float* __restrict__ x,
                                              const float* __restrict__ gw,
                                              float* __restrict__ tval,
                                              int* __restrict__ tidx) {
  const int be0 = blockIdx.x, b0 = be0 >> 5, e = be0 & 31;
  const int t = threadIdx.x, w = t >> 6, lane = t & 63;

  __shared__ float  cv[64];
  __shared__ int    cix[64];
  __shared__ double wsum[4];
  __shared__ float  smax;
  __shared__ int    gci[16];
  __shared__ float  glc[16];
  __shared__ double ginv;

  const int kb = lane * 16;
  float gwl[16];
  *(float4*)&gwl[0]  = *(const float4*)&gw[(size_t)e * ND + kb];
  *(float4*)&gwl[4]  = *(const float4*)&gw[(size_t)e * ND + kb + 4];
  *(float4*)&gwl[8]  = *(const float4*)&gw[(size_t)e * ND + kb + 8];
  *(float4*)&gwl[12] = *(const float4*)&gw[(size_t)e * ND + kb + 12];

  for (int rep = 0; rep < TREP; ++rep) {
    const int b  = (b0 + rep * 4) & 63;
    const int be = b * 32 + e;
    const float* row = logitsT + (size_t)be * NS;

    float v[8]; int si[8];
#pragma unroll
    for (int j = 0; j < 8; ++j) {
      const int s = w * 512 + lane + j * 64;
      v[j] = row[s]; si[j] = s;
    }
#pragma unroll
    for (int i = 0; i < 7; ++i)
#pragma unroll
      for (int j = 0; j < 7 - i; ++j) {
        const bool sw = (v[j + 1] > v[j]) || (v[j + 1] == v[j] && si[j + 1] < si[j]);
        const float tv = sw ? v[j + 1] : v[j];
        const int   ti = sw ? si[j + 1] : si[j];
        v[j + 1] = sw ? v[j] : v[j + 1];  si[j + 1] = sw ? si[j] : si[j + 1];
        v[j] = tv;  si[j] = ti;
      }
    const float mxl = v[0];
    double s8 = 1.0;
#pragma unroll
    for (int j = 1; j < 8; ++j) s8 += (double)expf(v[j] - mxl);

    for (int r = 0; r < 16; ++r) {
      float bp = v[0]; int bi = si[0]; int bl = lane;
#pragma unroll
      for (int off = 1; off < 64; off <<= 1) {
        const float op = __shfl_xor(bp, off);
        const int   oi = __shfl_xor(bi, off);
        const int   ol = __shfl_xor(bl, off);
        if (op > bp || (op == bp && oi < bi)) { bp = op; bi = oi; bl = ol; }
      }
      if (lane == 0) { cv[w * 16 + r] = bp; cix[w * 16 + r] = bi; }
      if (lane == bl) {
        v[0]=v[1]; v[1]=v[2]; v[2]=v[3]; v[3]=v[4]; v[4]=v[5]; v[5]=v[6]; v[6]=v[7]; v[7]=-INFINITY;
        si[0]=si[1]; si[1]=si[2]; si[2]=si[3]; si[3]=si[4]; si[4]=si[5]; si[5]=si[6]; si[6]=si[7]; si[7]=0x7fffffff;
      }
    }
    __syncthreads();
    if (w == 0) {
      float mv = cv[lane]; int mi = cix[lane];
      for (int r = 0; r < 16; ++r) {
        float bp = mv; int bi = mi; int bl = lane;
#pragma unroll
        for (int off = 1; off < 64; off <<= 1) {
          const float op = __shfl_xor(bp, off);
          const int   oi = __shfl_xor(bi, off);
          const int   ol = __shfl_xor(bl, off);
          if (op > bp || (op == bp && oi < bi)) { bp = op; bi = oi; bl = ol; }
        }
        if (lane == 0) { gci[r] = bi; if (r == 0) smax = bp; }
        if (lane == bl) { mv = -INFINITY; mi = 0x7fffffff; }
      }
    }
    __syncthreads();
    const float mx = smax;
    double lsum = s8 * (double)expf(mxl - mx);
#pragma unroll
    for (int off = 32; off; off >>= 1) lsum += __shfl_xor(lsum, off);
    if (lane == 0) wsum[w] = lsum;
    __syncthreads();
    if (t == 0) ginv = 1.0 / (wsum[0] + wsum[1] + wsum[2] + wsum[3]);

#pragma unroll
    for (int q = 0; q < 4; ++q) {
      const int c = w * 4 + q;
      const int ciq = gci[c];
      const float* xr = x + ((size_t)b * NS + ciq) * ND + kb;
      float xv[16];
      *(float4*)&xv[0]  = *(const float4*)&xr[0];
      *(float4*)&xv[4]  = *(const float4*)&xr[4];
      *(float4*)&xv[8]  = *(const float4*)&xr[8];
      *(float4*)&xv[12] = *(const float4*)&xr[12];
      double d = 0.0;
#pragma unroll
      for (int j2 = 0; j2 < 16; ++j2) d += (double)xv[j2] * (double)gwl[j2];
#pragma unroll
      for (int off = 32; off; off >>= 1) d += __shfl_xor(d, off);
      if (lane == 0) glc[c] = (float)d;
    }
    __syncthreads();
    if (t < 16) {
      const float mylc = glc[t]; const int myci = gci[t];
      int rank = 0;
#pragma unroll
      for (int c2 = 0; c2 < 16; ++c2) {
        if (c2 == t) continue;
        rank += (glc[c2] > mylc) || (glc[c2] == mylc && gci[c2] < myci);
      }
      if (rank < 8) {
        tval[be * 8 + rank] = (float)((double)expf(mylc - mx) * ginv);
        tidx[be * 8 + rank] = myci;
      }
    }
    __syncthreads();
  }
}

// ---------------------------------------------------------------------------
// Kernel 3: mux/merge -> single bf16 A as pre-swizzled 64x64 tiles.
// ---------------------------------------------------------------------------
__global__ __launch_bounds__(256) void k_merge(const float* __restrict__ x,
                                               const float* __restrict__ tval,
                                               const int* __restrict__ tidx,
                                               unsigned short* __restrict__ A1) {
  const int be = blockIdx.x;
  const int b  = be >> 5;
  const int e  = be & 31;
  const int t  = threadIdx.x;
  float4 acc = {0.f, 0.f, 0.f, 0.f};
#pragma unroll
  for (int k = 0; k < 8; ++k) {
    float v = tval[be * 8 + k];
    int   s = tidx[be * 8 + k];
    float4 xv = *(const float4*)&x[((size_t)b * NS + s) * ND + t * 4];
    acc.x += v * xv.x; acc.y += v * xv.y; acc.z += v * xv.z; acc.w += v * xv.w;
  }
  const int kt = t >> 4;
  const int g  = (t & 15) >> 1;
  const size_t off = ((size_t)(e * 16 + kt)) * 4096 + b * 64 + ((g ^ (b & 7)) << 3) + (t & 1) * 4;
  unsigned short h4[4] = {f2bf_rne(acc.x), f2bf_rne(acc.y), f2bf_rne(acc.z), f2bf_rne(acc.w)};
  *(ushort4*)&A1[off] = *(const ushort4*)h4;
}

// ---------------------------------------------------------------------------
// Kernels 4/5: per-expert FFN GEMM (R9 form).
// ---------------------------------------------------------------------------
template <int K, int N, bool GELU>
__global__ __launch_bounds__(256, 4) void k_ffn(const unsigned short* __restrict__ AT,
                                                const float* __restrict__ W,
                                                unsigned short* __restrict__ OT,
                                                float* __restrict__ Of) {
  constexpr int KT = K / 64;
  const int e  = blockIdx.y;
  const int n0 = blockIdx.x * 64;
  const int t  = threadIdx.x, l = t & 63, w = t >> 6;
  const int wr = w >> 1, wc = w & 1;

  __shared__ char smem[32768];

  const float* Wbase = W + (size_t)e * (K + 1) * N;
  f32x4 acc[2][2] = {};

  const int wn  = l;
  const int wk0 = w * 8;
  float wreg[2][8];

  auto issueW = [&](int kt) {
    const float* Wg = Wbase + (size_t)(kt * 64) * N + n0 + wn;
#pragma unroll
    for (int rn = 0; rn < 2; ++rn)
#pragma unroll
      for (int j = 0; j < 8; ++j)
        wreg[rn][j] = Wg[(size_t)(wk0 + rn * 32 + j) * N];
  };
  auto issueA = [&](int kt, int dst) {
    const unsigned short* at = AT + ((size_t)(e * KT + kt)) * 4096;
    char* Ab = smem + dst * 8192;
#pragma unroll
    for (int p = 0; p < 2; ++p)
      gload_lds16(at + p * 2048 + t * 8, Ab + p * 4096 + w * 1024);
  };
  auto commitW = [&](int dst) {
    short* Bb = (short*)(smem + 16384 + dst * 8192);
#pragma unroll
    for (int rn = 0; rn < 2; ++rn) {
      const int kr = (wk0 + rn * 32) >> 3;
      unsigned short s8[8];
#pragma unroll
      for (int j = 0; j < 8; ++j) s8[j] = f2bf_rne(wreg[rn][j]);
      *(uint4*)&Bb[wn * 64 + ((kr ^ (wn & 7)) << 3)] = *(const uint4*)s8;
    }
  };
  auto mfma_phase = [&](int cur) {
    const short* Ab = (const short*)(smem + cur * 8192);
    const short* Bb = (const short*)(smem + 16384 + cur * 8192);
#pragma unroll
    for (int ks = 0; ks < 2; ++ks) {
      const int g8 = ks * 4 + (l >> 4);
      bf16x8 a[2], bb[2];
#pragma unroll
      for (int mf = 0; mf < 2; ++mf) {
        const int m = wr * 32 + mf * 16 + (l & 15);
        a[mf] = *(const bf16x8*)&Ab[m * 64 + ((g8 ^ (m & 7)) << 3)];
      }
#pragma unroll
      for (int nf = 0; nf < 2; ++nf) {
        const int n = wc * 32 + nf * 16 + (l & 15);
        bb[nf] = *(const bf16x8*)&Bb[n * 64 + ((g8 ^ (n & 7)) << 3)];
      }
#pragma unroll
      for (int mf = 0; mf < 2; ++mf)
#pragma unroll
        for (int nf = 0; nf < 2; ++nf)
          acc[mf][nf] = __builtin_amdgcn_mfma_f32_16x16x32_bf16(a[mf], bb[nf], acc[mf][nf], 0, 0, 0);
    }
  };

  issueW(0); issueA(0, 0);
  commitW(0);
  __syncthreads();
  int cur = 0;
  for (int kt = 0; kt < KT; ++kt) {
    const bool more = (kt + 1 < KT);
    if (more) { issueW(kt + 1); issueA(kt + 1, cur ^ 1); }
    mfma_phase(cur);
    if (more) commitW(cur ^ 1);
    __syncthreads();
    cur ^= 1;
  }

  if (GELU) {
    unsigned short* transU = (unsigned short*)smem;  // [64][72]
#pragma unroll
    for (int nf = 0; nf < 2; ++nf) {
      const int c = wc * 32 + nf * 16 + (l & 15);
      const float bias = Wbase[(size_t)K * N + n0 + c];
#pragma unroll
      for (int mf = 0; mf < 2; ++mf)
#pragma unroll
        for (int j = 0; j < 4; ++j) {
          const int m = wr * 32 + mf * 16 + (l >> 4) * 4 + j;
          float vv = acc[mf][nf][j] + bias;
          vv = 0.5f * vv * (1.0f + erff(vv * 0.70710678118654752440f));
          transU[m * 72 + c] = f2bf_rne(vv);
        }
    }
    __syncthreads();
    const int m  = t >> 2;
    const int c0 = (t & 3) * 16;
    const size_t tb = ((size_t)(e * (N / 64) + blockIdx.x)) * 4096;
    uint4 v0 = *(const uint4*)&transU[m * 72 + c0];
    uint4 v1 = *(const uint4*)&transU[m * 72 + c0 + 8];
    const int g0 = c0 >> 3;
    *(uint4*)&OT[tb + m * 64 + ((g0 ^ (m & 7)) << 3)]       = v0;
    *(uint4*)&OT[tb + m * 64 + (((g0 + 1) ^ (m & 7)) << 3)] = v1;
  } else {
    float* transF = (float*)smem;  // [64][68]
#pragma unroll
    for (int nf = 0; nf < 2; ++nf) {
      const int c = wc * 32 + nf * 16 + (l & 15);
      const float bias = Wbase[(size_t)K * N + n0 + c];
#pragma unroll
      for (int mf = 0; mf < 2; ++mf)
#pragma unroll
        for (int j = 0; j < 4; ++j) {
          const int m = wr * 32 + mf * 16 + (l >> 4) * 4 + j;
          transF[m * 68 + c] = acc[mf][nf][j] + bias;
        }
    }
    __syncthreads();
    const int m  = t >> 2;
    const int c0 = (t & 3) * 16;
    float* og = Of + ((size_t)m * NE + e) * ND + n0 + c0;
    *(float4*)&og[0]  = *(const float4*)&transF[m * 68 + c0];
    *(float4*)&og[4]  = *(const float4*)&transF[m * 68 + c0 + 4];
    *(float4*)&og[8]  = *(const float4*)&transF[m * 68 + c0 + 8];
    *(float4*)&og[12] = *(const float4*)&transF[m * 68 + c0 + 12];
  }
}

// ---------------------------------------------------------------------------
// Kernel 6: demux/scatter, 8 tokens per block (R9 form).
// ---------------------------------------------------------------------------
__global__ __launch_bounds__(256) void k_scatter(const float* __restrict__ Obuf,
                                                 const float* __restrict__ tval,
                                                 const int* __restrict__ tidx,
                                                 float* __restrict__ out) {
  const int s0 = blockIdx.x * 8;
  const int b  = blockIdx.y;
  const int t  = threadIdx.x;
  const int w  = t >> 6;
  __shared__ unsigned long long masks[8][4];

  const int myIdx = tidx[b * 256 + t];
#pragma unroll
  for (int j = 0; j < 8; ++j) {
    unsigned long long m = __ballot(myIdx == s0 + j);
    if ((t & 63) == 0) masks[j][w] = m;
  }
  __syncthreads();

#pragma unroll
  for (int j = 0; j < 8; ++j) {
    float4 acc = {0.f, 0.f, 0.f, 0.f};
#pragma unroll
    for (int q = 0; q < 4; ++q) {
      unsigned long long mm = masks[j][q];
      while (mm) {
        int bit = __ffsll(mm) - 1;
        mm &= mm - 1;
        int r = q * 64 + bit;
        float v = tval[b * 256 + r];
        const float4 ov = *(const float4*)&Obuf[((size_t)b * NE + (r >> 3)) * ND + t * 4];
        acc.x += v * ov.x; acc.y += v * ov.y; acc.z += v * ov.z; acc.w += v * ov.w;
      }
    }
    *(float4*)&out[((size_t)b * NS + s0 + j) * ND + t * 4] = acc;
  }
}

// ---------------------------------------------------------------------------
extern "C" void kernel_launch(void* const* d_in, const int* in_sizes, int n_in,
                              void* d_out, int out_size, void* d_ws, size_t ws_size,
                              hipStream_t stream) {
  const float* x  = (const float*)d_in[0];
  const float* gw = (const float*)d_in[1];
  const float* w1 = (const float*)d_in[3];
  const float* w2 = (const float*)d_in[4];
  float* out = (float*)d_out;

  char* ws = (char*)d_ws;
  float* logitsT     = (float*)ws;                         // 16,777,216 B
  float* tval        = (float*)(ws + 16777216);            //     65,536 B
  int*   tidx        = (int*)  (ws + 16842752);            //     65,536 B
  unsigned short* A1 = (unsigned short*)(ws + 16908288);   //  4,194,304 B (bf16 tiles)
  unsigned short* Hb = (unsigned short*)(ws + 21102592);   // 16,777,216 B (bf16 tiles)
  float* Obuf        = (float*)(ws + 37879808);            //  8,388,608 B

  k_gate_mfma<<<dim3(NS / 128, NB), 256, 0, stream>>>(x, gw, logitsT);
  k_topk<<<NB * NE, 256, 0, stream>>>(logitsT, x, gw, tval, tidx);
  k_merge<<<NB * NE, 256, 0, stream>>>(x, tval, tidx, A1);
  k_ffn<ND, NH, true ><<<dim3(NH / 64, NE), 256, 0, stream>>>(A1, w1, Hb, nullptr);
  k_ffn<NH, ND, false><<<dim3(ND / 64, NE), 256, 0, stream>>>(Hb, w2, nullptr, Obuf);
  k_scatter<<<dim3(NS / 8, NB), 256, 0, stream>>>(Obuf, tval, tidx, out);
}

// Round 12
// 514.146 us; speedup vs baseline: 2.8497x; 2.8497x over previous
//
#include <hip/hip_runtime.h>
#include <hip/hip_bf16.h>
#include <math.h>

constexpr int NB = 64;     // batch
constexpr int NS = 2048;   // tokens
constexpr int ND = 1024;   // model dim
constexpr int NE = 32;     // experts
constexpr int NH = 4096;   // hidden
constexpr int NK = 8;      // top-k tokens per expert

typedef short bf16x8 __attribute__((ext_vector_type(8)));
typedef float f32x4  __attribute__((ext_vector_type(4)));

__device__ __forceinline__ unsigned short f2bf_rne(float v) {
  unsigned u = __builtin_bit_cast(unsigned, v);
  u += 0x7fffu + ((u >> 16) & 1u);
  return (unsigned short)(u >> 16);
}

__device__ __forceinline__ void gload_lds16(const void* g, void* l) {
  __builtin_amdgcn_global_load_lds(
      (const __attribute__((address_space(1))) unsigned*)g,
      (__attribute__((address_space(3))) unsigned*)l, 16, 0, 0);
}

// order-preserving float->u32 (monotone), and inverse
__device__ __forceinline__ unsigned ford(float f) {
  unsigned u = __builtin_bit_cast(unsigned, f);
  return (u & 0x80000000u) ? ~u : (u | 0x80000000u);
}
__device__ __forceinline__ float finv(unsigned o) {
  unsigned u = (o & 0x80000000u) ? (o & 0x7fffffffu) : ~o;
  return __builtin_bit_cast(float, u);
}

// ---------------------------------------------------------------------------
// Kernel 1: gating GEMM, single-term bf16 MFMA, 64-token tiles, 24KB LDS
// (~6 blocks/CU). T4 pipeline: two register sets, raw s_barrier with
// lgkmcnt-only (no vmcnt drain), x2-unrolled K-loop.
// ---------------------------------------------------------------------------
__global__ __launch_bounds__(256) void k_gate_mfma(const float* __restrict__ x,
                                                   const float* __restrict__ gw,
                                                   float* __restrict__ logitsT) {
  const int b  = blockIdx.y;
  const int s0 = blockIdx.x * 64;
  const int t  = threadIdx.x;
  const int l  = t & 63;
  const int w  = t >> 6;

  __shared__ char smem[24576];
  // A buf d: smem + d*8192 ([64][64] swz bf16); B buf d: smem + 16384 + d*4096
  float* trans = (float*)smem;  // [64][33] f32 epilogue (reuses A bufs)

  f32x4 acc[2] = {};

  const int ar  = t >> 2;          // A staging: row 0..63 (4 thr/row)
  const int ac4 = (t & 3) * 16;    // A staging: col base (4 float4)
  const int ge  = t >> 3;          // B staging: expert row 0..31
  const int gk  = (t & 7) * 8;     // B staging: col base (8 floats)

  float xA[4][4], xB[4][4], wA[8], wB[8];

  auto issue = [&](int kt, float (&xreg)[4][4], float (&wreg)[8]) {
    const int k0 = kt * 64;
    const float* xr = &x[((size_t)b * NS + s0 + ar) * ND + k0 + ac4];
#pragma unroll
    for (int j = 0; j < 4; ++j) *(float4*)xreg[j] = *(const float4*)&xr[j * 4];
    *(float4*)&wreg[0] = *(const float4*)&gw[(size_t)ge * ND + k0 + gk];
    *(float4*)&wreg[4] = *(const float4*)&gw[(size_t)ge * ND + k0 + gk + 4];
  };
  auto commit = [&](int dst, float (&xreg)[4][4], float (&wreg)[8]) {
    short* Ah = (short*)(smem + dst * 8192);
    short* Bh = (short*)(smem + 16384 + dst * 4096);
#pragma unroll
    for (int j = 0; j < 4; ++j) {
      unsigned short h[4];
#pragma unroll
      for (int q = 0; q < 4; ++q) h[q] = f2bf_rne(xreg[j][q]);
      const int col = ac4 + j * 4;
      *(ushort4*)&Ah[ar * 64 + (col ^ ((ar & 7) * 8))] = *(const ushort4*)h;
    }
    unsigned short h8[8];
#pragma unroll
    for (int j = 0; j < 8; ++j) h8[j] = f2bf_rne(wreg[j]);
    *(uint4*)&Bh[ge * 64 + (gk ^ ((ge & 7) * 8))] = *(const uint4*)h8;
  };
  auto mfma_phase = [&](int cur) {
    const short* Ah = (const short*)(smem + cur * 8192);
    const short* Bh = (const short*)(smem + 16384 + cur * 4096);
#pragma unroll
    for (int ks = 0; ks < 2; ++ks) {
      const int koff = ks * 32 + (l >> 4) * 8;
      const int rl = w * 16 + (l & 15);
      bf16x8 a = *(const bf16x8*)&Ah[rl * 64 + (koff ^ ((rl & 7) * 8))];
#pragma unroll
      for (int nf = 0; nf < 2; ++nf) {
        const int n = nf * 16 + (l & 15);
        bf16x8 bb = *(const bf16x8*)&Bh[n * 64 + (koff ^ ((n & 7) * 8))];
        acc[nf] = __builtin_amdgcn_mfma_f32_16x16x32_bf16(a, bb, acc[nf], 0, 0, 0);
      }
    }
  };
  auto bar = [&]() {
    asm volatile("s_waitcnt lgkmcnt(0)" ::: "memory");
    __builtin_amdgcn_s_barrier();
    __builtin_amdgcn_sched_barrier(0);
  };

  issue(0, xA, wA);
  issue(1, xB, wB);
  commit(0, xA, wA);
  bar();

  for (int kt = 0; kt < ND / 64; kt += 2) {
    if (kt + 2 < ND / 64) issue(kt + 2, xA, wA);
    commit(1, xB, wB);
    mfma_phase(0);
    bar();
    if (kt + 3 < ND / 64) issue(kt + 3, xB, wB);
    if (kt + 2 < ND / 64) commit(0, xA, wA);
    mfma_phase(1);
    bar();
  }

  // transpose epilogue through LDS for coalesced [e][s] stores
#pragma unroll
  for (int nf = 0; nf < 2; ++nf)
#pragma unroll
    for (int j = 0; j < 4; ++j) {
      const int sl = w * 16 + (l >> 4) * 4 + j;
      const int ec = nf * 16 + (l & 15);
      trans[sl * 33 + ec] = acc[nf][j];
    }
  __syncthreads();
  const int eo = t >> 3, sc = (t & 7) * 8;
#pragma unroll
  for (int q = 0; q < 2; ++q) {
    float4 v;
    v.x = trans[(sc + q * 4 + 0) * 33 + eo];
    v.y = trans[(sc + q * 4 + 1) * 33 + eo];
    v.z = trans[(sc + q * 4 + 2) * 33 + eo];
    v.w = trans[(sc + q * 4 + 3) * 33 + eo];
    *(float4*)&logitsT[((size_t)b * NE + eo) * NS + s0 + sc + q * 4] = v;
  }
}

// ---------------------------------------------------------------------------
// Kernel 2: topk — packed-u64 keys (val ord | inv idx) for cheap argmax pops;
// parallel rank-select for the 64->16 merge; sorted-order denominator and
// fp64 recheck unchanged (identical selection & arithmetic to R9).
// ---------------------------------------------------------------------------
__global__ __launch_bounds__(256) void k_topk(const float* __restrict__ logitsT,
                                              const float* __restrict__ x,
                                              const float* __restrict__ gw,
                                              float* __restrict__ tval,
                                              int* __restrict__ tidx) {
  const int be = blockIdx.x, b = be >> 5, e = be & 31;
  const float* row = logitsT + (size_t)be * NS;
  const int t = threadIdx.x, w = t >> 6, lane = t & 63;

  __shared__ unsigned long long cvp[64];   // per-wave top-16 packed
  __shared__ unsigned long long gcp[16];   // global top-16 packed
  __shared__ int    gci[16];
  __shared__ float  glc[16];
  __shared__ double wsum[4];
  __shared__ float  smax_s;
  __shared__ double ginv;

  // per-lane load + sort (float,idx) desc — identical to R9
  float v[8]; int si[8];
#pragma unroll
  for (int j = 0; j < 8; ++j) {
    const int s = w * 512 + lane + j * 64;
    v[j] = row[s]; si[j] = s;
  }
#pragma unroll
  for (int i = 0; i < 7; ++i)
#pragma unroll
    for (int j = 0; j < 7 - i; ++j) {
      const bool sw = (v[j + 1] > v[j]) || (v[j + 1] == v[j] && si[j + 1] < si[j]);
      const float tv = sw ? v[j + 1] : v[j];
      const int   ti = sw ? si[j + 1] : si[j];
      v[j + 1] = sw ? v[j] : v[j + 1];  si[j + 1] = sw ? si[j] : si[j + 1];
      v[j] = tv;  si[j] = ti;
    }
  const float mxl = v[0];
  double s8 = 1.0;
#pragma unroll
  for (int j = 1; j < 8; ++j) s8 += (double)expf(v[j] - mxl);

  // pack sorted list into u64 keys
  unsigned long long p[8];
#pragma unroll
  for (int j = 0; j < 8; ++j)
    p[j] = ((unsigned long long)ford(v[j]) << 32) | (0xFFFFFFFFu - (unsigned)si[j]);

  // per-wave top-16 by argmax-pop (pop test: head == wave max; keys unique)
  for (int r = 0; r < 16; ++r) {
    unsigned long long m = p[0];
#pragma unroll
    for (int off = 1; off < 64; off <<= 1) {
      const unsigned long long o = __shfl_xor(m, off);
      m = (o > m) ? o : m;
    }
    if (lane == 0) cvp[w * 16 + r] = m;
    if (p[0] == m) {
      p[0]=p[1]; p[1]=p[2]; p[2]=p[3]; p[3]=p[4]; p[4]=p[5]; p[5]=p[6]; p[6]=p[7]; p[7]=0ull;
    }
  }
  __syncthreads();

  // 64 -> 16 merge: parallel rank-select (wave 0; broadcast LDS reads)
  if (w == 0) {
    const unsigned long long mine = cvp[lane];
    int rank = 0;
#pragma unroll
    for (int j = 0; j < 64; ++j) rank += (cvp[j] > mine);
    if (rank < 16) {
      gcp[rank] = mine;
      gci[rank] = (int)(0xFFFFFFFFu - (unsigned)(mine & 0xFFFFFFFFu));
      if (rank == 0) smax_s = finv((unsigned)(mine >> 32));
    }
  }
  __syncthreads();

  const float mx = smax_s;
  double lsum = s8 * (double)expf(mxl - mx);
#pragma unroll
  for (int off = 32; off; off >>= 1) lsum += __shfl_xor(lsum, off);
  if (lane == 0) wsum[w] = lsum;
  __syncthreads();
  if (t == 0) ginv = 1.0 / (wsum[0] + wsum[1] + wsum[2] + wsum[3]);

  // fp64 recheck: wave w -> candidates 4w..4w+3
  const int kb = lane * 16;
  float gwl[16];
  *(float4*)&gwl[0]  = *(const float4*)&gw[(size_t)e * ND + kb];
  *(float4*)&gwl[4]  = *(const float4*)&gw[(size_t)e * ND + kb + 4];
  *(float4*)&gwl[8]  = *(const float4*)&gw[(size_t)e * ND + kb + 8];
  *(float4*)&gwl[12] = *(const float4*)&gw[(size_t)e * ND + kb + 12];
#pragma unroll
  for (int q = 0; q < 4; ++q) {
    const int c = w * 4 + q;
    const int ciq = gci[c];
    const float* xr = x + ((size_t)b * NS + ciq) * ND + kb;
    float xv[16];
    *(float4*)&xv[0]  = *(const float4*)&xr[0];
    *(float4*)&xv[4]  = *(const float4*)&xr[4];
    *(float4*)&xv[8]  = *(const float4*)&xr[8];
    *(float4*)&xv[12] = *(const float4*)&xr[12];
    double d = 0.0;
#pragma unroll
    for (int j2 = 0; j2 < 16; ++j2) d += (double)xv[j2] * (double)gwl[j2];
#pragma unroll
    for (int off = 32; off; off >>= 1) d += __shfl_xor(d, off);
    if (lane == 0) glc[c] = (float)d;
  }
  __syncthreads();
  if (t < 16) {
    const float mylc = glc[t]; const int myci = gci[t];
    int rank = 0;
#pragma unroll
    for (int c2 = 0; c2 < 16; ++c2) {
      if (c2 == t) continue;
      rank += (glc[c2] > mylc) || (glc[c2] == mylc && gci[c2] < myci);
    }
    if (rank < 8) {
      tval[be * 8 + rank] = (float)((double)expf(mylc - mx) * ginv);
      tidx[be * 8 + rank] = myci;
    }
  }
}

// ---------------------------------------------------------------------------
// Kernel 3: mux/merge -> single bf16 A as pre-swizzled 64x64 tiles.
// ---------------------------------------------------------------------------
__global__ __launch_bounds__(256) void k_merge(const float* __restrict__ x,
                                               const float* __restrict__ tval,
                                               const int* __restrict__ tidx,
                                               unsigned short* __restrict__ A1) {
  const int be = blockIdx.x;
  const int b  = be >> 5;
  const int e  = be & 31;
  const int t  = threadIdx.x;
  float4 acc = {0.f, 0.f, 0.f, 0.f};
#pragma unroll
  for (int k = 0; k < 8; ++k) {
    float v = tval[be * 8 + k];
    int   s = tidx[be * 8 + k];
    float4 xv = *(const float4*)&x[((size_t)b * NS + s) * ND + t * 4];
    acc.x += v * xv.x; acc.y += v * xv.y; acc.z += v * xv.z; acc.w += v * xv.w;
  }
  const int kt = t >> 4;
  const int g  = (t & 15) >> 1;
  const size_t off = ((size_t)(e * 16 + kt)) * 4096 + b * 64 + ((g ^ (b & 7)) << 3) + (t & 1) * 4;
  unsigned short h4[4] = {f2bf_rne(acc.x), f2bf_rne(acc.y), f2bf_rne(acc.z), f2bf_rne(acc.w)};
  *(ushort4*)&A1[off] = *(const ushort4*)h4;
}

// ---------------------------------------------------------------------------
// Kernels 4/5: per-expert FFN GEMM, single-bf16 MFMA, BN=64, 32KB LDS (R9).
// ---------------------------------------------------------------------------
template <int K, int N, bool GELU>
__global__ __launch_bounds__(256, 4) void k_ffn(const unsigned short* __restrict__ AT,
                                                const float* __restrict__ W,
                                                unsigned short* __restrict__ OT,
                                                float* __restrict__ Of) {
  constexpr int KT = K / 64;
  const int e  = blockIdx.y;
  const int n0 = blockIdx.x * 64;
  const int t  = threadIdx.x, l = t & 63, w = t >> 6;
  const int wr = w >> 1, wc = w & 1;

  __shared__ char smem[32768];

  const float* Wbase = W + (size_t)e * (K + 1) * N;
  f32x4 acc[2][2] = {};

  const int wn  = l;
  const int wk0 = w * 8;
  float wreg[2][8];

  auto issueW = [&](int kt) {
    const float* Wg = Wbase + (size_t)(kt * 64) * N + n0 + wn;
#pragma unroll
    for (int rn = 0; rn < 2; ++rn)
#pragma unroll
      for (int j = 0; j < 8; ++j)
        wreg[rn][j] = Wg[(size_t)(wk0 + rn * 32 + j) * N];
  };
  auto issueA = [&](int kt, int dst) {
    const unsigned short* at = AT + ((size_t)(e * KT + kt)) * 4096;
    char* Ab = smem + dst * 8192;
#pragma unroll
    for (int p = 0; p < 2; ++p)
      gload_lds16(at + p * 2048 + t * 8, Ab + p * 4096 + w * 1024);
  };
  auto commitW = [&](int dst) {
    short* Bb = (short*)(smem + 16384 + dst * 8192);
#pragma unroll
    for (int rn = 0; rn < 2; ++rn) {
      const int kr = (wk0 + rn * 32) >> 3;
      unsigned short s8[8];
#pragma unroll
      for (int j = 0; j < 8; ++j) s8[j] = f2bf_rne(wreg[rn][j]);
      *(uint4*)&Bb[wn * 64 + ((kr ^ (wn & 7)) << 3)] = *(const uint4*)s8;
    }
  };
  auto mfma_phase = [&](int cur) {
    const short* Ab = (const short*)(smem + cur * 8192);
    const short* Bb = (const short*)(smem + 16384 + cur * 8192);
#pragma unroll
    for (int ks = 0; ks < 2; ++ks) {
      const int g8 = ks * 4 + (l >> 4);
      bf16x8 a[2], bb[2];
#pragma unroll
      for (int mf = 0; mf < 2; ++mf) {
        const int m = wr * 32 + mf * 16 + (l & 15);
        a[mf] = *(const bf16x8*)&Ab[m * 64 + ((g8 ^ (m & 7)) << 3)];
      }
#pragma unroll
      for (int nf = 0; nf < 2; ++nf) {
        const int n = wc * 32 + nf * 16 + (l & 15);
        bb[nf] = *(const bf16x8*)&Bb[n * 64 + ((g8 ^ (n & 7)) << 3)];
      }
#pragma unroll
      for (int mf = 0; mf < 2; ++mf)
#pragma unroll
        for (int nf = 0; nf < 2; ++nf)
          acc[mf][nf] = __builtin_amdgcn_mfma_f32_16x16x32_bf16(a[mf], bb[nf], acc[mf][nf], 0, 0, 0);
    }
  };

  issueW(0); issueA(0, 0);
  commitW(0);
  __syncthreads();
  int cur = 0;
  for (int kt = 0; kt < KT; ++kt) {
    const bool more = (kt + 1 < KT);
    if (more) { issueW(kt + 1); issueA(kt + 1, cur ^ 1); }
    mfma_phase(cur);
    if (more) commitW(cur ^ 1);
    __syncthreads();
    cur ^= 1;
  }

  if (GELU) {
    unsigned short* transU = (unsigned short*)smem;  // [64][72]
#pragma unroll
    for (int nf = 0; nf < 2; ++nf) {
      const int c = wc * 32 + nf * 16 + (l & 15);
      const float bias = Wbase[(size_t)K * N + n0 + c];
#pragma unroll
      for (int mf = 0; mf < 2; ++mf)
#pragma unroll
        for (int j = 0; j < 4; ++j) {
          const int m = wr * 32 + mf * 16 + (l >> 4) * 4 + j;
          float vv = acc[mf][nf][j] + bias;
          vv = 0.5f * vv * (1.0f + erff(vv * 0.70710678118654752440f));
          transU[m * 72 + c] = f2bf_rne(vv);
        }
    }
    __syncthreads();
    const int m  = t >> 2;
    const int c0 = (t & 3) * 16;
    const size_t tb = ((size_t)(e * (N / 64) + blockIdx.x)) * 4096;
    uint4 v0 = *(const uint4*)&transU[m * 72 + c0];
    uint4 v1 = *(const uint4*)&transU[m * 72 + c0 + 8];
    const int g0 = c0 >> 3;
    *(uint4*)&OT[tb + m * 64 + ((g0 ^ (m & 7)) << 3)]       = v0;
    *(uint4*)&OT[tb + m * 64 + (((g0 + 1) ^ (m & 7)) << 3)] = v1;
  } else {
    float* transF = (float*)smem;  // [64][68]
#pragma unroll
    for (int nf = 0; nf < 2; ++nf) {
      const int c = wc * 32 + nf * 16 + (l & 15);
      const float bias = Wbase[(size_t)K * N + n0 + c];
#pragma unroll
      for (int mf = 0; mf < 2; ++mf)
#pragma unroll
        for (int j = 0; j < 4; ++j) {
          const int m = wr * 32 + mf * 16 + (l >> 4) * 4 + j;
          transF[m * 68 + c] = acc[mf][nf][j] + bias;
        }
    }
    __syncthreads();
    const int m  = t >> 2;
    const int c0 = (t & 3) * 16;
    float* og = Of + ((size_t)m * NE + e) * ND + n0 + c0;
    *(float4*)&og[0]  = *(const float4*)&transF[m * 68 + c0];
    *(float4*)&og[4]  = *(const float4*)&transF[m * 68 + c0 + 4];
    *(float4*)&og[8]  = *(const float4*)&transF[m * 68 + c0 + 8];
    *(float4*)&og[12] = *(const float4*)&transF[m * 68 + c0 + 12];
  }
}

// ---------------------------------------------------------------------------
// Kernel 6: demux/scatter, 8 tokens per block (R9 form).
// ---------------------------------------------------------------------------
__global__ __launch_bounds__(256) void k_scatter(const float* __restrict__ Obuf,
                                                 const float* __restrict__ tval,
                                                 const int* __restrict__ tidx,
                                                 float* __restrict__ out) {
  const int s0 = blockIdx.x * 8;
  const int b  = blockIdx.y;
  const int t  = threadIdx.x;
  const int w  = t >> 6;
  __shared__ unsigned long long masks[8][4];

  const int myIdx = tidx[b * 256 + t];
#pragma unroll
  for (int j = 0; j < 8; ++j) {
    unsigned long long m = __ballot(myIdx == s0 + j);
    if ((t & 63) == 0) masks[j][w] = m;
  }
  __syncthreads();

#pragma unroll
  for (int j = 0; j < 8; ++j) {
    float4 acc = {0.f, 0.f, 0.f, 0.f};
#pragma unroll
    for (int q = 0; q < 4; ++q) {
      unsigned long long mm = masks[j][q];
      while (mm) {
        int bit = __ffsll(mm) - 1;
        mm &= mm - 1;
        int r = q * 64 + bit;
        float v = tval[b * 256 + r];
        const float4 ov = *(const float4*)&Obuf[((size_t)b * NE + (r >> 3)) * ND + t * 4];
        acc.x += v * ov.x; acc.y += v * ov.y; acc.z += v * ov.z; acc.w += v * ov.w;
      }
    }
    *(float4*)&out[((size_t)b * NS + s0 + j) * ND + t * 4] = acc;
  }
}

// ---------------------------------------------------------------------------
extern "C" void kernel_launch(void* const* d_in, const int* in_sizes, int n_in,
                              void* d_out, int out_size, void* d_ws, size_t ws_size,
                              hipStream_t stream) {
  const float* x  = (const float*)d_in[0];
  const float* gw = (const float*)d_in[1];
  const float* w1 = (const float*)d_in[3];
  const float* w2 = (const float*)d_in[4];
  float* out = (float*)d_out;

  char* ws = (char*)d_ws;
  float* logitsT     = (float*)ws;                         // 16,777,216 B
  float* tval        = (float*)(ws + 16777216);            //     65,536 B
  int*   tidx        = (int*)  (ws + 16842752);            //     65,536 B
  unsigned short* A1 = (unsigned short*)(ws + 16908288);   //  4,194,304 B (bf16 tiles)
  unsigned short* Hb = (unsigned short*)(ws + 21102592);   // 16,777,216 B (bf16 tiles)
  float* Obuf        = (float*)(ws + 37879808);            //  8,388,608 B

  k_gate_mfma<<<dim3(NS / 64, NB), 256, 0, stream>>>(x, gw, logitsT);
  k_topk<<<NB * NE, 256, 0, stream>>>(logitsT, x, gw, tval, tidx);
  k_merge<<<NB * NE, 256, 0, stream>>>(x, tval, tidx, A1);
  k_ffn<ND, NH, true ><<<dim3(NH / 64, NE), 256, 0, stream>>>(A1, w1, Hb, nullptr);
  k_ffn<NH, ND, false><<<dim3(ND / 64, NE), 256, 0, stream>>>(Hb, w2, nullptr, Obuf);
  k_scatter<<<dim3(NS / 8, NB), 256, 0, stream>>>(Obuf, tval, tidx, out);
}

// Round 13
// 506.350 us; speedup vs baseline: 2.8935x; 1.0154x over previous
//
#include <hip/hip_runtime.h>
#include <hip/hip_bf16.h>
#include <math.h>

constexpr int NB = 64;     // batch
constexpr int NS = 2048;   // tokens
constexpr int ND = 1024;   // model dim
constexpr int NE = 32;     // experts
constexpr int NH = 4096;   // hidden
constexpr int NK = 8;      // top-k tokens per expert

typedef short bf16x8 __attribute__((ext_vector_type(8)));
typedef float f32x4  __attribute__((ext_vector_type(4)));

__device__ __forceinline__ unsigned short f2bf_rne(float v) {
  unsigned u = __builtin_bit_cast(unsigned, v);
  u += 0x7fffu + ((u >> 16) & 1u);
  return (unsigned short)(u >> 16);
}

__device__ __forceinline__ void gload_lds16(const void* g, void* l) {
  __builtin_amdgcn_global_load_lds(
      (const __attribute__((address_space(1))) unsigned*)g,
      (__attribute__((address_space(3))) unsigned*)l, 16, 0, 0);
}

// order-preserving float->u32 (monotone), and inverse
__device__ __forceinline__ unsigned ford(float f) {
  unsigned u = __builtin_bit_cast(unsigned, f);
  return (u & 0x80000000u) ? ~u : (u | 0x80000000u);
}
__device__ __forceinline__ float finv(unsigned o) {
  unsigned u = (o & 0x80000000u) ? (o & 0x7fffffffu) : ~o;
  return __builtin_bit_cast(float, u);
}

// ---------------------------------------------------------------------------
// Kernel 1: gating GEMM, single-term bf16 MFMA, 64-token tiles, 24KB LDS
// (~6 blocks/CU). T4 pipeline: two register sets, raw s_barrier with
// lgkmcnt-only (no vmcnt drain), x2-unrolled K-loop. (R12, unchanged.)
// ---------------------------------------------------------------------------
__global__ __launch_bounds__(256) void k_gate_mfma(const float* __restrict__ x,
                                                   const float* __restrict__ gw,
                                                   float* __restrict__ logitsT) {
  const int b  = blockIdx.y;
  const int s0 = blockIdx.x * 64;
  const int t  = threadIdx.x;
  const int l  = t & 63;
  const int w  = t >> 6;

  __shared__ char smem[24576];
  float* trans = (float*)smem;

  f32x4 acc[2] = {};

  const int ar  = t >> 2;
  const int ac4 = (t & 3) * 16;
  const int ge  = t >> 3;
  const int gk  = (t & 7) * 8;

  float xA[4][4], xB[4][4], wA[8], wB[8];

  auto issue = [&](int kt, float (&xreg)[4][4], float (&wreg)[8]) {
    const int k0 = kt * 64;
    const float* xr = &x[((size_t)b * NS + s0 + ar) * ND + k0 + ac4];
#pragma unroll
    for (int j = 0; j < 4; ++j) *(float4*)xreg[j] = *(const float4*)&xr[j * 4];
    *(float4*)&wreg[0] = *(const float4*)&gw[(size_t)ge * ND + k0 + gk];
    *(float4*)&wreg[4] = *(const float4*)&gw[(size_t)ge * ND + k0 + gk + 4];
  };
  auto commit = [&](int dst, float (&xreg)[4][4], float (&wreg)[8]) {
    short* Ah = (short*)(smem + dst * 8192);
    short* Bh = (short*)(smem + 16384 + dst * 4096);
#pragma unroll
    for (int j = 0; j < 4; ++j) {
      unsigned short h[4];
#pragma unroll
      for (int q = 0; q < 4; ++q) h[q] = f2bf_rne(xreg[j][q]);
      const int col = ac4 + j * 4;
      *(ushort4*)&Ah[ar * 64 + (col ^ ((ar & 7) * 8))] = *(const ushort4*)h;
    }
    unsigned short h8[8];
#pragma unroll
    for (int j = 0; j < 8; ++j) h8[j] = f2bf_rne(wreg[j]);
    *(uint4*)&Bh[ge * 64 + (gk ^ ((ge & 7) * 8))] = *(const uint4*)h8;
  };
  auto mfma_phase = [&](int cur) {
    const short* Ah = (const short*)(smem + cur * 8192);
    const short* Bh = (const short*)(smem + 16384 + cur * 4096);
#pragma unroll
    for (int ks = 0; ks < 2; ++ks) {
      const int koff = ks * 32 + (l >> 4) * 8;
      const int rl = w * 16 + (l & 15);
      bf16x8 a = *(const bf16x8*)&Ah[rl * 64 + (koff ^ ((rl & 7) * 8))];
#pragma unroll
      for (int nf = 0; nf < 2; ++nf) {
        const int n = nf * 16 + (l & 15);
        bf16x8 bb = *(const bf16x8*)&Bh[n * 64 + (koff ^ ((n & 7) * 8))];
        acc[nf] = __builtin_amdgcn_mfma_f32_16x16x32_bf16(a, bb, acc[nf], 0, 0, 0);
      }
    }
  };
  auto bar = [&]() {
    asm volatile("s_waitcnt lgkmcnt(0)" ::: "memory");
    __builtin_amdgcn_s_barrier();
    __builtin_amdgcn_sched_barrier(0);
  };

  issue(0, xA, wA);
  issue(1, xB, wB);
  commit(0, xA, wA);
  bar();

  for (int kt = 0; kt < ND / 64; kt += 2) {
    if (kt + 2 < ND / 64) issue(kt + 2, xA, wA);
    commit(1, xB, wB);
    mfma_phase(0);
    bar();
    if (kt + 3 < ND / 64) issue(kt + 3, xB, wB);
    if (kt + 2 < ND / 64) commit(0, xA, wA);
    mfma_phase(1);
    bar();
  }

#pragma unroll
  for (int nf = 0; nf < 2; ++nf)
#pragma unroll
    for (int j = 0; j < 4; ++j) {
      const int sl = w * 16 + (l >> 4) * 4 + j;
      const int ec = nf * 16 + (l & 15);
      trans[sl * 33 + ec] = acc[nf][j];
    }
  __syncthreads();
  const int eo = t >> 3, sc = (t & 7) * 8;
#pragma unroll
  for (int q = 0; q < 2; ++q) {
    float4 v;
    v.x = trans[(sc + q * 4 + 0) * 33 + eo];
    v.y = trans[(sc + q * 4 + 1) * 33 + eo];
    v.z = trans[(sc + q * 4 + 2) * 33 + eo];
    v.w = trans[(sc + q * 4 + 3) * 33 + eo];
    *(float4*)&logitsT[((size_t)b * NE + eo) * NS + s0 + sc + q * 4] = v;
  }
}

// ---------------------------------------------------------------------------
// Kernel 2: topk + FUSED merge. Selection/denominator/recheck identical to
// R12; after selection, (val,idx) pairs go to LDS and the same block runs the
// mux accumulation (L2-hot x rows) and writes the pre-swizzled A1 tile.
// ---------------------------------------------------------------------------
__global__ __launch_bounds__(256) void k_topk_merge(const float* __restrict__ logitsT,
                                                    const float* __restrict__ x,
                                                    const float* __restrict__ gw,
                                                    float* __restrict__ tval,
                                                    int* __restrict__ tidx,
                                                    unsigned short* __restrict__ A1) {
  const int be = blockIdx.x, b = be >> 5, e = be & 31;
  const float* row = logitsT + (size_t)be * NS;
  const int t = threadIdx.x, w = t >> 6, lane = t & 63;

  __shared__ unsigned long long cvp[64];   // per-wave top-16 packed
  __shared__ int    gci[16];
  __shared__ float  glc[16];
  __shared__ double wsum[4];
  __shared__ float  smax_s;
  __shared__ double ginv;
  __shared__ float  selv[8];
  __shared__ int    seli[8];

  // per-lane load + sort (float,idx) desc
  float v[8]; int si[8];
#pragma unroll
  for (int j = 0; j < 8; ++j) {
    const int s = w * 512 + lane + j * 64;
    v[j] = row[s]; si[j] = s;
  }
#pragma unroll
  for (int i = 0; i < 7; ++i)
#pragma unroll
    for (int j = 0; j < 7 - i; ++j) {
      const bool sw = (v[j + 1] > v[j]) || (v[j + 1] == v[j] && si[j + 1] < si[j]);
      const float tv = sw ? v[j + 1] : v[j];
      const int   ti = sw ? si[j + 1] : si[j];
      v[j + 1] = sw ? v[j] : v[j + 1];  si[j + 1] = sw ? si[j] : si[j + 1];
      v[j] = tv;  si[j] = ti;
    }
  const float mxl = v[0];
  double s8 = 1.0;
#pragma unroll
  for (int j = 1; j < 8; ++j) s8 += (double)expf(v[j] - mxl);

  // pack sorted list into u64 keys
  unsigned long long p[8];
#pragma unroll
  for (int j = 0; j < 8; ++j)
    p[j] = ((unsigned long long)ford(v[j]) << 32) | (0xFFFFFFFFu - (unsigned)si[j]);

  // per-wave top-16 by argmax-pop
  for (int r = 0; r < 16; ++r) {
    unsigned long long m = p[0];
#pragma unroll
    for (int off = 1; off < 64; off <<= 1) {
      const unsigned long long o = __shfl_xor(m, off);
      m = (o > m) ? o : m;
    }
    if (lane == 0) cvp[w * 16 + r] = m;
    if (p[0] == m) {
      p[0]=p[1]; p[1]=p[2]; p[2]=p[3]; p[3]=p[4]; p[4]=p[5]; p[5]=p[6]; p[6]=p[7]; p[7]=0ull;
    }
  }
  __syncthreads();

  // 64 -> 16 merge: parallel rank-select (wave 0)
  if (w == 0) {
    const unsigned long long mine = cvp[lane];
    int rank = 0;
#pragma unroll
    for (int j = 0; j < 64; ++j) rank += (cvp[j] > mine);
    if (rank < 16) {
      gci[rank] = (int)(0xFFFFFFFFu - (unsigned)(mine & 0xFFFFFFFFu));
      if (rank == 0) smax_s = finv((unsigned)(mine >> 32));
    }
  }
  __syncthreads();

  const float mx = smax_s;
  double lsum = s8 * (double)expf(mxl - mx);
#pragma unroll
  for (int off = 32; off; off >>= 1) lsum += __shfl_xor(lsum, off);
  if (lane == 0) wsum[w] = lsum;
  __syncthreads();
  if (t == 0) ginv = 1.0 / (wsum[0] + wsum[1] + wsum[2] + wsum[3]);

  // fp64 recheck: wave w -> candidates 4w..4w+3
  const int kb = lane * 16;
  float gwl[16];
  *(float4*)&gwl[0]  = *(const float4*)&gw[(size_t)e * ND + kb];
  *(float4*)&gwl[4]  = *(const float4*)&gw[(size_t)e * ND + kb + 4];
  *(float4*)&gwl[8]  = *(const float4*)&gw[(size_t)e * ND + kb + 8];
  *(float4*)&gwl[12] = *(const float4*)&gw[(size_t)e * ND + kb + 12];
#pragma unroll
  for (int q = 0; q < 4; ++q) {
    const int c = w * 4 + q;
    const int ciq = gci[c];
    const float* xr = x + ((size_t)b * NS + ciq) * ND + kb;
    float xv[16];
    *(float4*)&xv[0]  = *(const float4*)&xr[0];
    *(float4*)&xv[4]  = *(const float4*)&xr[4];
    *(float4*)&xv[8]  = *(const float4*)&xr[8];
    *(float4*)&xv[12] = *(const float4*)&xr[12];
    double d = 0.0;
#pragma unroll
    for (int j2 = 0; j2 < 16; ++j2) d += (double)xv[j2] * (double)gwl[j2];
#pragma unroll
    for (int off = 32; off; off >>= 1) d += __shfl_xor(d, off);
    if (lane == 0) glc[c] = (float)d;
  }
  __syncthreads();
  if (t < 16) {
    const float mylc = glc[t]; const int myci = gci[t];
    int rank = 0;
#pragma unroll
    for (int c2 = 0; c2 < 16; ++c2) {
      if (c2 == t) continue;
      rank += (glc[c2] > mylc) || (glc[c2] == mylc && gci[c2] < myci);
    }
    if (rank < 8) {
      const float pv = (float)((double)expf(mylc - mx) * ginv);
      tval[be * 8 + rank] = pv;
      tidx[be * 8 + rank] = myci;
      selv[rank] = pv;
      seli[rank] = myci;
    }
  }
  __syncthreads();

  // ---- fused mux/merge: acc over rank order (identical to old k_merge) ----
  float4 acc4 = {0.f, 0.f, 0.f, 0.f};
#pragma unroll
  for (int k = 0; k < 8; ++k) {
    const float vv = selv[k];
    const int   ss = seli[k];
    const float4 xv4 = *(const float4*)&x[((size_t)b * NS + ss) * ND + t * 4];
    acc4.x += vv * xv4.x; acc4.y += vv * xv4.y;
    acc4.z += vv * xv4.z; acc4.w += vv * xv4.w;
  }
  const int kt = t >> 4;
  const int g  = (t & 15) >> 1;
  const size_t off = ((size_t)(e * 16 + kt)) * 4096 + b * 64 + ((g ^ (b & 7)) << 3) + (t & 1) * 4;
  unsigned short h4[4] = {f2bf_rne(acc4.x), f2bf_rne(acc4.y), f2bf_rne(acc4.z), f2bf_rne(acc4.w)};
  *(ushort4*)&A1[off] = *(const ushort4*)h4;
}

// ---------------------------------------------------------------------------
// Kernels 3/4: per-expert FFN GEMM, single-bf16 MFMA, BN=64, 32KB LDS (R9).
// ---------------------------------------------------------------------------
template <int K, int N, bool GELU>
__global__ __launch_bounds__(256, 4) void k_ffn(const unsigned short* __restrict__ AT,
                                                const float* __restrict__ W,
                                                unsigned short* __restrict__ OT,
                                                float* __restrict__ Of) {
  constexpr int KT = K / 64;
  const int e  = blockIdx.y;
  const int n0 = blockIdx.x * 64;
  const int t  = threadIdx.x, l = t & 63, w = t >> 6;
  const int wr = w >> 1, wc = w & 1;

  __shared__ char smem[32768];

  const float* Wbase = W + (size_t)e * (K + 1) * N;
  f32x4 acc[2][2] = {};

  const int wn  = l;
  const int wk0 = w * 8;
  float wreg[2][8];

  auto issueW = [&](int kt) {
    const float* Wg = Wbase + (size_t)(kt * 64) * N + n0 + wn;
#pragma unroll
    for (int rn = 0; rn < 2; ++rn)
#pragma unroll
      for (int j = 0; j < 8; ++j)
        wreg[rn][j] = Wg[(size_t)(wk0 + rn * 32 + j) * N];
  };
  auto issueA = [&](int kt, int dst) {
    const unsigned short* at = AT + ((size_t)(e * KT + kt)) * 4096;
    char* Ab = smem + dst * 8192;
#pragma unroll
    for (int p = 0; p < 2; ++p)
      gload_lds16(at + p * 2048 + t * 8, Ab + p * 4096 + w * 1024);
  };
  auto commitW = [&](int dst) {
    short* Bb = (short*)(smem + 16384 + dst * 8192);
#pragma unroll
    for (int rn = 0; rn < 2; ++rn) {
      const int kr = (wk0 + rn * 32) >> 3;
      unsigned short s8[8];
#pragma unroll
      for (int j = 0; j < 8; ++j) s8[j] = f2bf_rne(wreg[rn][j]);
      *(uint4*)&Bb[wn * 64 + ((kr ^ (wn & 7)) << 3)] = *(const uint4*)s8;
    }
  };
  auto mfma_phase = [&](int cur) {
    const short* Ab = (const short*)(smem + cur * 8192);
    const short* Bb = (const short*)(smem + 16384 + cur * 8192);
#pragma unroll
    for (int ks = 0; ks < 2; ++ks) {
      const int g8 = ks * 4 + (l >> 4);
      bf16x8 a[2], bb[2];
#pragma unroll
      for (int mf = 0; mf < 2; ++mf) {
        const int m = wr * 32 + mf * 16 + (l & 15);
        a[mf] = *(const bf16x8*)&Ab[m * 64 + ((g8 ^ (m & 7)) << 3)];
      }
#pragma unroll
      for (int nf = 0; nf < 2; ++nf) {
        const int n = wc * 32 + nf * 16 + (l & 15);
        bb[nf] = *(const bf16x8*)&Bb[n * 64 + ((g8 ^ (n & 7)) << 3)];
      }
#pragma unroll
      for (int mf = 0; mf < 2; ++mf)
#pragma unroll
        for (int nf = 0; nf < 2; ++nf)
          acc[mf][nf] = __builtin_amdgcn_mfma_f32_16x16x32_bf16(a[mf], bb[nf], acc[mf][nf], 0, 0, 0);
    }
  };

  issueW(0); issueA(0, 0);
  commitW(0);
  __syncthreads();
  int cur = 0;
  for (int kt = 0; kt < KT; ++kt) {
    const bool more = (kt + 1 < KT);
    if (more) { issueW(kt + 1); issueA(kt + 1, cur ^ 1); }
    mfma_phase(cur);
    if (more) commitW(cur ^ 1);
    __syncthreads();
    cur ^= 1;
  }

  if (GELU) {
    unsigned short* transU = (unsigned short*)smem;  // [64][72]
#pragma unroll
    for (int nf = 0; nf < 2; ++nf) {
      const int c = wc * 32 + nf * 16 + (l & 15);
      const float bias = Wbase[(size_t)K * N + n0 + c];
#pragma unroll
      for (int mf = 0; mf < 2; ++mf)
#pragma unroll
        for (int j = 0; j < 4; ++j) {
          const int m = wr * 32 + mf * 16 + (l >> 4) * 4 + j;
          float vv = acc[mf][nf][j] + bias;
          vv = 0.5f * vv * (1.0f + erff(vv * 0.70710678118654752440f));
          transU[m * 72 + c] = f2bf_rne(vv);
        }
    }
    __syncthreads();
    const int m  = t >> 2;
    const int c0 = (t & 3) * 16;
    const size_t tb = ((size_t)(e * (N / 64) + blockIdx.x)) * 4096;
    uint4 v0 = *(const uint4*)&transU[m * 72 + c0];
    uint4 v1 = *(const uint4*)&transU[m * 72 + c0 + 8];
    const int g0 = c0 >> 3;
    *(uint4*)&OT[tb + m * 64 + ((g0 ^ (m & 7)) << 3)]       = v0;
    *(uint4*)&OT[tb + m * 64 + (((g0 + 1) ^ (m & 7)) << 3)] = v1;
  } else {
    float* transF = (float*)smem;  // [64][68]
#pragma unroll
    for (int nf = 0; nf < 2; ++nf) {
      const int c = wc * 32 + nf * 16 + (l & 15);
      const float bias = Wbase[(size_t)K * N + n0 + c];
#pragma unroll
      for (int mf = 0; mf < 2; ++mf)
#pragma unroll
        for (int j = 0; j < 4; ++j) {
          const int m = wr * 32 + mf * 16 + (l >> 4) * 4 + j;
          transF[m * 68 + c] = acc[mf][nf][j] + bias;
        }
    }
    __syncthreads();
    const int m  = t >> 2;
    const int c0 = (t & 3) * 16;
    float* og = Of + ((size_t)m * NE + e) * ND + n0 + c0;
    *(float4*)&og[0]  = *(const float4*)&transF[m * 68 + c0];
    *(float4*)&og[4]  = *(const float4*)&transF[m * 68 + c0 + 4];
    *(float4*)&og[8]  = *(const float4*)&transF[m * 68 + c0 + 8];
    *(float4*)&og[12] = *(const float4*)&transF[m * 68 + c0 + 12];
  }
}

// ---------------------------------------------------------------------------
// Kernel 5: demux/scatter, 8 tokens per block; deterministic fixed-order
// accumulation; zero-fills unpicked tokens.
// ---------------------------------------------------------------------------
__global__ __launch_bounds__(256) void k_scatter(const float* __restrict__ Obuf,
                                                 const float* __restrict__ tval,
                                                 const int* __restrict__ tidx,
                                                 float* __restrict__ out) {
  const int s0 = blockIdx.x * 8;
  const int b  = blockIdx.y;
  const int t  = threadIdx.x;
  const int w  = t >> 6;
  __shared__ unsigned long long masks[8][4];

  const int myIdx = tidx[b * 256 + t];
#pragma unroll
  for (int j = 0; j < 8; ++j) {
    unsigned long long m = __ballot(myIdx == s0 + j);
    if ((t & 63) == 0) masks[j][w] = m;
  }
  __syncthreads();

#pragma unroll
  for (int j = 0; j < 8; ++j) {
    float4 acc = {0.f, 0.f, 0.f, 0.f};
#pragma unroll
    for (int q = 0; q < 4; ++q) {
      unsigned long long mm = masks[j][q];
      while (mm) {
        int bit = __ffsll(mm) - 1;
        mm &= mm - 1;
        int r = q * 64 + bit;
        float v = tval[b * 256 + r];
        const float4 ov = *(const float4*)&Obuf[((size_t)b * NE + (r >> 3)) * ND + t * 4];
        acc.x += v * ov.x; acc.y += v * ov.y; acc.z += v * ov.z; acc.w += v * ov.w;
      }
    }
    *(float4*)&out[((size_t)b * NS + s0 + j) * ND + t * 4] = acc;
  }
}

// ---------------------------------------------------------------------------
extern "C" void kernel_launch(void* const* d_in, const int* in_sizes, int n_in,
                              void* d_out, int out_size, void* d_ws, size_t ws_size,
                              hipStream_t stream) {
  const float* x  = (const float*)d_in[0];
  const float* gw = (const float*)d_in[1];
  const float* w1 = (const float*)d_in[3];
  const float* w2 = (const float*)d_in[4];
  float* out = (float*)d_out;

  char* ws = (char*)d_ws;
  float* logitsT     = (float*)ws;                         // 16,777,216 B
  float* tval        = (float*)(ws + 16777216);            //     65,536 B
  int*   tidx        = (int*)  (ws + 16842752);            //     65,536 B
  unsigned short* A1 = (unsigned short*)(ws + 16908288);   //  4,194,304 B (bf16 tiles)
  unsigned short* Hb = (unsigned short*)(ws + 21102592);   // 16,777,216 B (bf16 tiles)
  float* Obuf        = (float*)(ws + 37879808);            //  8,388,608 B

  k_gate_mfma<<<dim3(NS / 64, NB), 256, 0, stream>>>(x, gw, logitsT);
  k_topk_merge<<<NB * NE, 256, 0, stream>>>(logitsT, x, gw, tval, tidx, A1);
  k_ffn<ND, NH, true ><<<dim3(NH / 64, NE), 256, 0, stream>>>(A1, w1, Hb, nullptr);
  k_ffn<NH, ND, false><<<dim3(ND / 64, NE), 256, 0, stream>>>(Hb, w2, nullptr, Obuf);
  k_scatter<<<dim3(NS / 8, NB), 256, 0, stream>>>(Obuf, tval, tidx, out);
}